// Round 18
// baseline (1001.818 us; speedup 1.0000x reference)
//
#include <hip/hip_runtime.h>

#define BN 8
#define NN 4096
#define CC 64
#define MM 1024
#define KK 64
#define HH 128

typedef __attribute__((ext_vector_type(8))) short short8;
typedef __attribute__((ext_vector_type(4))) float f32x4;
typedef __attribute__((ext_vector_type(2))) float f32x2;
typedef __attribute__((ext_vector_type(2))) double f64x2;
typedef unsigned long long u64;
typedef unsigned int u32;

__device__ inline unsigned short f2bf(float f) {
  union { float f; unsigned u; } v; v.f = f;
  unsigned r = v.u + 0x7FFFu + ((v.u >> 16) & 1u);
  return (unsigned short)(r >> 16);
}

// squared distance with NO fma contraction, numpy op order: (dx*dx + dy*dy) + dz*dz
__device__ inline float sqd(float ax, float ay, float az, float bx, float by, float bz) {
  float dx = __fsub_rn(ax, bx), dy = __fsub_rn(ay, by), dz = __fsub_rn(az, bz);
  return __fadd_rn(__fadd_rn(__fmul_rn(dx, dx), __fmul_rn(dy, dy)), __fmul_rn(dz, dz));
}

// ---------------- weight prep: transpose + pad + bf16 ----------------
__global__ void prep_w(const float* __restrict__ W1, const float* __restrict__ W2,
                       short* __restrict__ W1T, short* __restrict__ W2T) {
  int t = blockIdx.x * 256 + threadIdx.x;
  if (t < 128 * 104) {
    int n = t / 104, k = t % 104;
    float v = (k < 67) ? W1[k * 128 + n] : 0.f;
    W1T[t] = (short)f2bf(v);
  }
  if (t < 128 * 136) {
    int n = t / 136, k = t % 136;
    float v = (k < 128) ? W2[k * 128 + n] : 0.f;
    W2T[t] = (short)f2bf(v);
  }
}

// ---- DPP-based wave max of f32 (result broadcast via readlane 63) ----
template <int CTRL, int RM>
__device__ __forceinline__ float dppf(float x) {
  int v = __builtin_amdgcn_update_dpp(0, __float_as_int(x), CTRL, RM, 0xF, false);
  return __int_as_float(v);
}

__device__ __forceinline__ float wave_fmax(float x) {
  x = fmaxf(x, dppf<0xB1, 0xF>(x));    // quad_perm xor1
  x = fmaxf(x, dppf<0x4E, 0xF>(x));    // quad_perm xor2
  x = fmaxf(x, dppf<0x141, 0xF>(x));   // row_half_mirror
  x = fmaxf(x, dppf<0x140, 0xF>(x));   // row_mirror
  x = fmaxf(x, dppf<0x142, 0xA>(x));   // row_bcast15 -> rows 1,3
  x = fmaxf(x, dppf<0x143, 0xC>(x));   // row_bcast31 -> rows 2,3
  return __int_as_float(__builtin_amdgcn_readlane(__float_as_int(x), 63));
}

// ---- DPP inclusive prefix-sum (add) across 64 lanes ----
__device__ __forceinline__ int wave_iscan_add(int c) {
  int v = c;
  v += __builtin_amdgcn_update_dpp(0, v, 0x111, 0xF, 0xF, true);  // row_shr:1
  v += __builtin_amdgcn_update_dpp(0, v, 0x112, 0xF, 0xF, true);  // row_shr:2
  v += __builtin_amdgcn_update_dpp(0, v, 0x114, 0xF, 0xF, true);  // row_shr:4
  v += __builtin_amdgcn_update_dpp(0, v, 0x118, 0xF, 0xF, true);  // row_shr:8
  v += __builtin_amdgcn_update_dpp(0, v, 0x142, 0xA, 0xF, true);  // row_bcast15 -> rows 1,3
  v += __builtin_amdgcn_update_dpp(0, v, 0x143, 0xC, 0xF, true);  // row_bcast31 -> rows 2,3
  return v;  // inclusive scan
}

// 2-level static select of one f32x2 out of a [4] array (indices all compile-time)
__device__ __forceinline__ f32x2 sel4(const f32x2 (&A)[4], u32 g) {
  f32x2 s0 = (g & 1) ? A[1] : A[0];
  f32x2 s1 = (g & 1) ? A[3] : A[2];
  return (g & 2) ? s1 : s0;
}

// load 8 points (24 floats, 16B-aligned base) into 4 f32x2-groups
__device__ __forceinline__ void load8(const float* Pl, f32x2 (&X)[4], f32x2 (&Y)[4],
                                      f32x2 (&Z)[4]) {
  f32x4 v0 = *(const f32x4*)(Pl + 0);
  f32x4 v1 = *(const f32x4*)(Pl + 4);
  f32x4 v2 = *(const f32x4*)(Pl + 8);
  f32x4 v3 = *(const f32x4*)(Pl + 12);
  f32x4 v4 = *(const f32x4*)(Pl + 16);
  f32x4 v5 = *(const f32x4*)(Pl + 20);
  X[0].x = v0[0]; Y[0].x = v0[1]; Z[0].x = v0[2];
  X[0].y = v0[3]; Y[0].y = v1[0]; Z[0].y = v1[1];
  X[1].x = v1[2]; Y[1].x = v1[3]; Z[1].x = v2[0];
  X[1].y = v2[1]; Y[1].y = v2[2]; Z[1].y = v2[3];
  X[2].x = v3[0]; Y[2].x = v3[1]; Z[2].x = v3[2];
  X[2].y = v3[3]; Y[2].y = v4[0]; Z[2].y = v4[1];
  X[3].x = v4[2]; Y[3].x = v4[3]; Z[3].x = v5[0];
  X[3].y = v5[1]; Y[3].y = v5[2]; Z[3].y = v5[3];
}

// 8-bit in-ball hitmask for 8 points at Pl (exact reference op order, no FMA)
__device__ __forceinline__ u32 hit8(const float* Pl, float cx, float cy, float cz) {
#pragma clang fp contract(off)
  f32x2 X[4], Y[4], Z[4];
  load8(Pl, X, Y, Z);
  f32x2 vcx; vcx.x = cx; vcx.y = cx;
  f32x2 vcy; vcy.x = cy; vcy.y = cy;
  f32x2 vcz; vcz.x = cz; vcz.y = cz;
  u32 h = 0;
#pragma unroll
  for (int j = 0; j < 4; ++j) {
    f32x2 dx = X[j] - vcx, dy = Y[j] - vcy, dz = Z[j] - vcz;
    f32x2 d2 = (dx * dx + dy * dy) + dz * dz;
    if (d2.x <= 0.04f) h |= 1u << (2 * j);
    if (d2.y <= 0.04f) h |= 1u << (2 * j + 1);
  }
  return h;
}

// ---------------- FPS: one block/batch, 512 threads, 8 pts/thread, carried coords -------
// Winner lane writes {key, x, y} + z selected from ITS OWN registers -> resolve is
// one parallel LDS hop (no dependent sp4 read). One barrier per step.
__global__ __launch_bounds__(512) void fps_k(const float* __restrict__ pos,
                                             float* __restrict__ centers) {
  const int b = blockIdx.x;
  const int tid = threadIdx.x;
  const int lane = tid & 63;
  const int wv = tid >> 6;                      // 0..7
  __shared__ __align__(16) f32x4 svrec[2][8];   // [pp][wave] {keylo,keyhi,x,y}
  __shared__ __align__(16) float svz[2][8];     // [pp][wave] z
  __shared__ float scen[MM * 3];                // 12 KB buffered centers

  const float* P = pos + (size_t)b * NN * 3;

  f32x2 X[4], Y[4], Z[4], M[4];
  load8(P + (size_t)tid * 24, X, Y, Z);
#pragma unroll
  for (int j = 0; j < 4; ++j)
    asm volatile("" : "+v"(X[j]), "+v"(Y[j]), "+v"(Z[j]));

  const float c0x = P[0], c0y = P[1], c0z = P[2];
  if (tid == 0) { scen[0] = c0x; scen[1] = c0y; scen[2] = c0z; }
  float mv;
  {
#pragma clang fp contract(off)
    f32x2 vcx; vcx.x = c0x; vcx.y = c0x;
    f32x2 vcy; vcy.x = c0y; vcy.y = c0y;
    f32x2 vcz; vcz.x = c0z; vcz.y = c0z;
#pragma unroll
    for (int j = 0; j < 4; ++j) {
      f32x2 dx = X[j] - vcx, dy = Y[j] - vcy, dz = Z[j] - vcz;
      M[j] = (dx * dx + dy * dy) + dz * dz;
    }
    f32x2 A0 = __builtin_elementwise_max(M[0], M[1]);
    f32x2 A1 = __builtin_elementwise_max(M[2], M[3]);
    f32x2 E = __builtin_elementwise_max(A0, A1);
    mv = fmaxf(E.x, E.y);
  }

  for (int m = 1; m < MM; ++m) {
    const int pp = m & 1;
    float wmax = wave_fmax(mv);
    u64 bal = __ballot(mv == wmax);
    int L = (int)__builtin_ctzll(bal);          // lowest lane = lowest point range
    // in-thread first-match element: descending overwrite, y before x at each j
    u32 e = 7u;
    if (M[3].y == wmax) e = 7u;
    if (M[3].x == wmax) e = 6u;
    if (M[2].y == wmax) e = 5u;
    if (M[2].x == wmax) e = 4u;
    if (M[1].y == wmax) e = 3u;
    if (M[1].x == wmax) e = 2u;
    if (M[0].y == wmax) e = 1u;
    if (M[0].x == wmax) e = 0u;
    // own coords of element e (static 2-level select + half pick)
    u32 g = e >> 1;
    f32x2 xs = sel4(X, g), ys = sel4(Y, g), zs = sel4(Z, g);
    float lx = (e & 1) ? xs.y : xs.x;
    float ly = (e & 1) ? ys.y : ys.x;
    float lz = (e & 1) ? zs.y : zs.x;
    if (lane == L) {
      u64 key = ((u64)__float_as_uint(wmax) << 32) | (u64)(u32)~(u32)(tid * 8 + (int)e);
      f32x2 kf = __builtin_bit_cast(f32x2, key);
      f32x4 rec; rec[0] = kf.x; rec[1] = kf.y; rec[2] = lx; rec[3] = ly;
      svrec[pp][wv] = rec;
      svz[pp][wv] = lz;
    }
    __syncthreads();
    // one parallel LDS hop: 8 records + 2 z-vectors
    f32x4 r0 = svrec[pp][0], r1 = svrec[pp][1], r2 = svrec[pp][2], r3 = svrec[pp][3];
    f32x4 r4 = svrec[pp][4], r5 = svrec[pp][5], r6 = svrec[pp][6], r7 = svrec[pp][7];
    f32x4 zv0 = *(const f32x4*)&svz[pp][0];
    f32x4 zv1 = *(const f32x4*)&svz[pp][4];
    f32x2 kf;
    kf.x = r0[0]; kf.y = r0[1]; double d0 = __builtin_bit_cast(double, kf);
    kf.x = r1[0]; kf.y = r1[1]; double d1 = __builtin_bit_cast(double, kf);
    kf.x = r2[0]; kf.y = r2[1]; double d2 = __builtin_bit_cast(double, kf);
    kf.x = r3[0]; kf.y = r3[1]; double d3 = __builtin_bit_cast(double, kf);
    kf.x = r4[0]; kf.y = r4[1]; double d4 = __builtin_bit_cast(double, kf);
    kf.x = r5[0]; kf.y = r5[1]; double d5 = __builtin_bit_cast(double, kf);
    kf.x = r6[0]; kf.y = r6[1]; double d6 = __builtin_bit_cast(double, kf);
    kf.x = r7[0]; kf.y = r7[1]; double d7 = __builtin_bit_cast(double, kf);
    double kb = fmax(fmax(fmax(d0, d1), fmax(d2, d3)), fmax(fmax(d4, d5), fmax(d6, d7)));
    u32 bp = ~(u32)__builtin_bit_cast(u64, kb);
    u32 w = bp >> 9;                            // winning wave (512 pts per wave)
    float ax0 = (w & 1) ? r1[2] : r0[2], ax1 = (w & 1) ? r3[2] : r2[2];
    float ax2 = (w & 1) ? r5[2] : r4[2], ax3 = (w & 1) ? r7[2] : r6[2];
    float bx0 = (w & 2) ? ax1 : ax0, bx1 = (w & 2) ? ax3 : ax2;
    const float ncx = (w & 4) ? bx1 : bx0;
    float ay0 = (w & 1) ? r1[3] : r0[3], ay1 = (w & 1) ? r3[3] : r2[3];
    float ay2 = (w & 1) ? r5[3] : r4[3], ay3 = (w & 1) ? r7[3] : r6[3];
    float by0 = (w & 2) ? ay1 : ay0, by1 = (w & 2) ? ay3 : ay2;
    const float ncy = (w & 4) ? by1 : by0;
    float az0 = (w & 1) ? zv0[1] : zv0[0], az1 = (w & 1) ? zv0[3] : zv0[2];
    float az2 = (w & 1) ? zv1[1] : zv1[0], az3 = (w & 1) ? zv1[3] : zv1[2];
    float bz0 = (w & 2) ? az1 : az0, bz1 = (w & 2) ? az3 : az2;
    const float ncz = (w & 4) ? bz1 : bz0;
    if (tid == 0) {
      scen[m * 3 + 0] = ncx;
      scen[m * 3 + 1] = ncy;
      scen[m * 3 + 2] = ncz;
    }
    {
#pragma clang fp contract(off)
      f32x2 vcx; vcx.x = ncx; vcx.y = ncx;
      f32x2 vcy; vcy.x = ncy; vcy.y = ncy;
      f32x2 vcz; vcz.x = ncz; vcz.y = ncz;
#pragma unroll
      for (int j = 0; j < 4; ++j) {
        f32x2 dx = X[j] - vcx, dy = Y[j] - vcy, dz = Z[j] - vcz;
        f32x2 d2 = (dx * dx + dy * dy) + dz * dz;
        M[j] = __builtin_elementwise_min(M[j], d2);
      }
      f32x2 A0 = __builtin_elementwise_max(M[0], M[1]);
      f32x2 A1 = __builtin_elementwise_max(M[2], M[3]);
      f32x2 E = __builtin_elementwise_max(A0, A1);
      mv = fmaxf(E.x, E.y);
    }
  }
  __syncthreads();
  for (int i = tid; i < MM * 3; i += 512)
    centers[(size_t)b * MM * 3 + i] = scen[i];
}

// ---------------- fused ball query + PointNetConv MLP: one block per center ----------------
// One-pass ball query: thread owns 16 contiguous points; DPP prefix-scan compaction.
__global__ __launch_bounds__(256) void sa_k(const float* __restrict__ x,
                                            const float* __restrict__ pos,
                                            const float* __restrict__ b1,
                                            const float* __restrict__ b2,
                                            const short* __restrict__ W1T,
                                            const short* __restrict__ W2T,
                                            const float* __restrict__ centers,
                                            float* __restrict__ out) {
  const int bid = blockIdx.x;
  const int cm = (bid & 7) * 1024 + (bid >> 3);   // XCD swizzle: one batch per XCD
  const int b = cm >> 10;
  const int tid = threadIdx.x;
  const int lane = tid & 63, wv = tid >> 6;
  const int l15 = lane & 15, lg = lane >> 4;

  __shared__ short s_feat[64][104];
  __shared__ short s_h1[64][136];
  __shared__ int s_nbr[64];
  __shared__ int s_wcnt[4];

  // --- weight fragments in registers (B-operand): row=n (lane&15), k contiguous 8 ---
  const int n0 = wv * 32;
  short8 w1f[2][3], w2f[2][4];
#pragma unroll
  for (int nt = 0; nt < 2; ++nt) {
    int row = n0 + nt * 16 + l15;
#pragma unroll
    for (int kt = 0; kt < 3; ++kt)
      w1f[nt][kt] = *reinterpret_cast<const short8*>(W1T + row * 104 + kt * 32 + lg * 8);
#pragma unroll
    for (int kt = 0; kt < 4; ++kt)
      w2f[nt][kt] = *reinterpret_cast<const short8*>(W2T + row * 136 + kt * 32 + lg * 8);
  }

  const float* Pb = pos + (size_t)b * NN * 3;
  const float cx = centers[(size_t)cm * 3 + 0];
  const float cy = centers[(size_t)cm * 3 + 1];
  const float cz = centers[(size_t)cm * 3 + 2];

  // --- one-pass ball query over own 16 points ---
  const int q0 = tid * 16;
  u32 hm = hit8(Pb + (size_t)q0 * 3, cx, cy, cz)
         | (hit8(Pb + (size_t)q0 * 3 + 24, cx, cy, cz) << 8);
  int c = __popc(hm);
  int inc = wave_iscan_add(c);
  if (lane == 63) s_wcnt[wv] = inc;           // wave total
  __syncthreads();
  int woff = 0, tot = 0;
#pragma unroll
  for (int w = 0; w < 4; ++w) {
    int t = s_wcnt[w];
    tot += t;
    if (w < wv) woff += t;
  }
  int cnt = tot > KK ? KK : tot;
  int slot = woff + inc - c;                  // exclusive, index-ordered
  // zero feat (pad cols + invalid rows) in same phase as s_nbr writes
  {
    int* fz = (int*)&s_feat[0][0];
    for (int i = tid; i < 64 * 104 / 2; i += 256) fz[i] = 0;
  }
#pragma unroll
  for (int i = 0; i < 16; ++i) {
    if (hm & (1u << i)) {
      if (slot < KK) s_nbr[slot] = q0 + i;
      ++slot;
    }
  }
  __syncthreads();

  // --- gather: 4 threads per neighbor, 16 feats each ---
  {
    const int j = tid >> 2, q = tid & 3;
    if (j < cnt) {
      int nj = s_nbr[j];
      const float* xr = x + ((size_t)b * NN + nj) * CC + q * 16;
      unsigned* dst = (unsigned*)&s_feat[j][q * 16];
#pragma unroll
      for (int v4 = 0; v4 < 4; ++v4) {
        f32x4 xv = *reinterpret_cast<const f32x4*>(xr + v4 * 4);
        unsigned lo0 = (unsigned)f2bf(xv[0]) | ((unsigned)f2bf(xv[1]) << 16);
        unsigned lo1 = (unsigned)f2bf(xv[2]) | ((unsigned)f2bf(xv[3]) << 16);
        dst[v4 * 2 + 0] = lo0;
        dst[v4 * 2 + 1] = lo1;
      }
      if (q == 0) {
        s_feat[j][64] = (short)f2bf(__fsub_rn(Pb[nj * 3 + 0], cx));
        s_feat[j][65] = (short)f2bf(__fsub_rn(Pb[nj * 3 + 1], cy));
        s_feat[j][66] = (short)f2bf(__fsub_rn(Pb[nj * 3 + 2], cz));
      }
    }
  }
  __syncthreads();

  // --- layer 1: feat[64x96] @ W1T -> h1[64][128] (per-wave 32 cols) ---
  f32x4 acc[4][2];
#pragma unroll
  for (int mt = 0; mt < 4; ++mt)
#pragma unroll
    for (int nt = 0; nt < 2; ++nt) acc[mt][nt] = (f32x4)0.f;

#pragma unroll
  for (int mt = 0; mt < 4; ++mt) {
    int arow = mt * 16 + l15;
#pragma unroll
    for (int kt = 0; kt < 3; ++kt) {
      short8 af = *reinterpret_cast<const short8*>(&s_feat[arow][kt * 32 + lg * 8]);
      acc[mt][0] = __builtin_amdgcn_mfma_f32_16x16x32_bf16(af, w1f[0][kt], acc[mt][0], 0, 0, 0);
      acc[mt][1] = __builtin_amdgcn_mfma_f32_16x16x32_bf16(af, w1f[1][kt], acc[mt][1], 0, 0, 0);
    }
  }

  // bias + relu -> bf16 h1 in LDS
#pragma unroll
  for (int mt = 0; mt < 4; ++mt) {
#pragma unroll
    for (int nt = 0; nt < 2; ++nt) {
      int col = n0 + nt * 16 + l15;
      float bias = b1[col];
#pragma unroll
      for (int r = 0; r < 4; ++r) {
        int row = mt * 16 + lg * 4 + r;
        float h = fmaxf(__fadd_rn(acc[mt][nt][r], bias), 0.f);
        s_h1[row][col] = (short)f2bf(h);
      }
    }
  }
  __syncthreads();

  // --- layer 2: h1[64x128] @ W2T ---
  f32x4 acc2[4][2];
#pragma unroll
  for (int mt = 0; mt < 4; ++mt)
#pragma unroll
    for (int nt = 0; nt < 2; ++nt) acc2[mt][nt] = (f32x4)0.f;

#pragma unroll
  for (int mt = 0; mt < 4; ++mt) {
    int arow = mt * 16 + l15;
#pragma unroll
    for (int kt = 0; kt < 4; ++kt) {
      short8 af = *reinterpret_cast<const short8*>(&s_h1[arow][kt * 32 + lg * 8]);
      acc2[mt][0] = __builtin_amdgcn_mfma_f32_16x16x32_bf16(af, w2f[0][kt], acc2[mt][0], 0, 0, 0);
      acc2[mt][1] = __builtin_amdgcn_mfma_f32_16x16x32_bf16(af, w2f[1][kt], acc2[mt][1], 0, 0, 0);
    }
  }

  // --- bias + relu + masked max over neighbors, then write out[cm][col] ---
#pragma unroll
  for (int nt = 0; nt < 2; ++nt) {
    int col = n0 + nt * 16 + l15;
    float bias = b2[col];
    float mx = -1e30f;
#pragma unroll
    for (int mt = 0; mt < 4; ++mt) {
#pragma unroll
      for (int r = 0; r < 4; ++r) {
        int row = mt * 16 + lg * 4 + r;
        float h = fmaxf(__fadd_rn(acc2[mt][nt][r], bias), 0.f);
        if (row < cnt) mx = fmaxf(mx, h);
      }
    }
    mx = fmaxf(mx, __shfl_xor(mx, 16));
    mx = fmaxf(mx, __shfl_xor(mx, 32));
    if (lg == 0) out[(size_t)cm * HH + col] = mx;
  }
}

extern "C" void kernel_launch(void* const* d_in, const int* in_sizes, int n_in,
                              void* d_out, int out_size, void* d_ws, size_t ws_size,
                              hipStream_t stream) {
  const float* x = (const float*)d_in[0];
  const float* pos = (const float*)d_in[1];
  const float* W1 = (const float*)d_in[2];
  const float* b1 = (const float*)d_in[3];
  const float* W2 = (const float*)d_in[4];
  const float* b2 = (const float*)d_in[5];

  float* out = (float*)d_out;
  float* centers = out + (size_t)BN * MM * HH;

  char* ws = (char*)d_ws;
  short* W1T = (short*)ws;                    // 128*104*2 = 26624 B
  short* W2T = (short*)(ws + 26624);          // 128*136*2 = 34816 B

  prep_w<<<68, 256, 0, stream>>>(W1, W2, W1T, W2T);
  fps_k<<<BN, 512, 0, stream>>>(pos, centers);
  sa_k<<<BN * MM, 256, 0, stream>>>(x, pos, b1, b2, W1T, W2T, centers, out);
}

// Round 19
// 676.052 us; speedup vs baseline: 1.4819x; 1.4819x over previous
//
#include <hip/hip_runtime.h>

#define BN 8
#define NN 4096
#define CC 64
#define MM 1024
#define KK 64
#define HH 128

typedef __attribute__((ext_vector_type(8))) short short8;
typedef __attribute__((ext_vector_type(4))) float f32x4;
typedef __attribute__((ext_vector_type(2))) float f32x2;
typedef __attribute__((ext_vector_type(2))) double f64x2;
typedef unsigned long long u64;
typedef unsigned int u32;

__device__ inline unsigned short f2bf(float f) {
  union { float f; unsigned u; } v; v.f = f;
  unsigned r = v.u + 0x7FFFu + ((v.u >> 16) & 1u);
  return (unsigned short)(r >> 16);
}

// squared distance with NO fma contraction, numpy op order: (dx*dx + dy*dy) + dz*dz
__device__ inline float sqd(float ax, float ay, float az, float bx, float by, float bz) {
  float dx = __fsub_rn(ax, bx), dy = __fsub_rn(ay, by), dz = __fsub_rn(az, bz);
  return __fadd_rn(__fadd_rn(__fmul_rn(dx, dx), __fmul_rn(dy, dy)), __fmul_rn(dz, dz));
}

// ---------------- weight prep: transpose + pad + bf16 ----------------
__global__ void prep_w(const float* __restrict__ W1, const float* __restrict__ W2,
                       short* __restrict__ W1T, short* __restrict__ W2T) {
  int t = blockIdx.x * 256 + threadIdx.x;
  if (t < 128 * 104) {
    int n = t / 104, k = t % 104;
    float v = (k < 67) ? W1[k * 128 + n] : 0.f;
    W1T[t] = (short)f2bf(v);
  }
  if (t < 128 * 136) {
    int n = t / 136, k = t % 136;
    float v = (k < 128) ? W2[k * 128 + n] : 0.f;
    W2T[t] = (short)f2bf(v);
  }
}

// ---- DPP-based wave max of f32 (result broadcast via readlane 63) ----
template <int CTRL, int RM>
__device__ __forceinline__ float dppf(float x) {
  int v = __builtin_amdgcn_update_dpp(0, __float_as_int(x), CTRL, RM, 0xF, false);
  return __int_as_float(v);
}

__device__ __forceinline__ float wave_fmax(float x) {
  x = fmaxf(x, dppf<0xB1, 0xF>(x));    // quad_perm xor1
  x = fmaxf(x, dppf<0x4E, 0xF>(x));    // quad_perm xor2
  x = fmaxf(x, dppf<0x141, 0xF>(x));   // row_half_mirror
  x = fmaxf(x, dppf<0x140, 0xF>(x));   // row_mirror
  x = fmaxf(x, dppf<0x142, 0xA>(x));   // row_bcast15 -> rows 1,3
  x = fmaxf(x, dppf<0x143, 0xC>(x));   // row_bcast31 -> rows 2,3
  return __int_as_float(__builtin_amdgcn_readlane(__float_as_int(x), 63));
}

// ---- DPP inclusive prefix-sum (add) across 64 lanes ----
__device__ __forceinline__ int wave_iscan_add(int c) {
  int v = c;
  v += __builtin_amdgcn_update_dpp(0, v, 0x111, 0xF, 0xF, true);  // row_shr:1
  v += __builtin_amdgcn_update_dpp(0, v, 0x112, 0xF, 0xF, true);  // row_shr:2
  v += __builtin_amdgcn_update_dpp(0, v, 0x114, 0xF, 0xF, true);  // row_shr:4
  v += __builtin_amdgcn_update_dpp(0, v, 0x118, 0xF, 0xF, true);  // row_shr:8
  v += __builtin_amdgcn_update_dpp(0, v, 0x142, 0xA, 0xF, true);  // row_bcast15 -> rows 1,3
  v += __builtin_amdgcn_update_dpp(0, v, 0x143, 0xC, 0xF, true);  // row_bcast31 -> rows 2,3
  return v;  // inclusive scan
}

// load 8 points (24 floats, 16B-aligned base) into 4 f32x2-groups
__device__ __forceinline__ void load8(const float* Pl, f32x2 (&X)[4], f32x2 (&Y)[4],
                                      f32x2 (&Z)[4]) {
  f32x4 v0 = *(const f32x4*)(Pl + 0);
  f32x4 v1 = *(const f32x4*)(Pl + 4);
  f32x4 v2 = *(const f32x4*)(Pl + 8);
  f32x4 v3 = *(const f32x4*)(Pl + 12);
  f32x4 v4 = *(const f32x4*)(Pl + 16);
  f32x4 v5 = *(const f32x4*)(Pl + 20);
  X[0].x = v0[0]; Y[0].x = v0[1]; Z[0].x = v0[2];
  X[0].y = v0[3]; Y[0].y = v1[0]; Z[0].y = v1[1];
  X[1].x = v1[2]; Y[1].x = v1[3]; Z[1].x = v2[0];
  X[1].y = v2[1]; Y[1].y = v2[2]; Z[1].y = v2[3];
  X[2].x = v3[0]; Y[2].x = v3[1]; Z[2].x = v3[2];
  X[2].y = v3[3]; Y[2].y = v4[0]; Z[2].y = v4[1];
  X[3].x = v4[2]; Y[3].x = v4[3]; Z[3].x = v5[0];
  X[3].y = v5[1]; Y[3].y = v5[2]; Z[3].y = v5[3];
}

// 8-bit in-ball hitmask for 8 points at Pl (exact reference op order, no FMA)
__device__ __forceinline__ u32 hit8(const float* Pl, float cx, float cy, float cz) {
#pragma clang fp contract(off)
  f32x2 X[4], Y[4], Z[4];
  load8(Pl, X, Y, Z);
  f32x2 vcx; vcx.x = cx; vcx.y = cx;
  f32x2 vcy; vcy.x = cy; vcy.y = cy;
  f32x2 vcz; vcz.x = cz; vcz.y = cz;
  u32 h = 0;
#pragma unroll
  for (int j = 0; j < 4; ++j) {
    f32x2 dx = X[j] - vcx, dy = Y[j] - vcy, dz = Z[j] - vcz;
    f32x2 d2 = (dx * dx + dy * dy) + dz * dz;
    if (d2.x <= 0.04f) h |= 1u << (2 * j);
    if (d2.y <= 0.04f) h |= 1u << (2 * j + 1);
  }
  return h;
}

// ---------------- FPS: one block/batch, 512 threads, 8 contiguous pts/thread (R11) -------
__global__ __launch_bounds__(512) void fps_k(const float* __restrict__ pos,
                                             float* __restrict__ centers) {
  const int b = blockIdx.x;
  const int tid = threadIdx.x;
  const int lane = tid & 63;
  const int wv = tid >> 6;                    // 0..7
  __shared__ __align__(16) double svk[2][8];  // ping-pong per-wave keys
  __shared__ __align__(16) f32x4 sp4[NN];     // 64 KB coords by point index
  __shared__ float scen[MM * 3];              // 12 KB buffered centers

  const float* P = pos + (size_t)b * NN * 3;

  f32x2 X[4], Y[4], Z[4], M[4];
  {
    const f32x4* Pv = (const f32x4*)(P + (size_t)tid * 24);
    f32x4 v0 = Pv[0], v1 = Pv[1], v2 = Pv[2], v3 = Pv[3], v4 = Pv[4], v5 = Pv[5];
    X[0].x = v0[0]; Y[0].x = v0[1]; Z[0].x = v0[2];
    X[0].y = v0[3]; Y[0].y = v1[0]; Z[0].y = v1[1];
    X[1].x = v1[2]; Y[1].x = v1[3]; Z[1].x = v2[0];
    X[1].y = v2[1]; Y[1].y = v2[2]; Z[1].y = v2[3];
    X[2].x = v3[0]; Y[2].x = v3[1]; Z[2].x = v3[2];
    X[2].y = v3[3]; Y[2].y = v4[0]; Z[2].y = v4[1];
    X[3].x = v4[2]; Y[3].x = v4[3]; Z[3].x = v5[0];
    X[3].y = v5[1]; Y[3].y = v5[2]; Z[3].y = v5[3];
  }
#pragma unroll
  for (int j = 0; j < 4; ++j) {
    int p0 = tid * 8 + 2 * j;
    f32x4 w;
    w[0] = X[j].x; w[1] = Y[j].x; w[2] = Z[j].x; w[3] = 0.f; sp4[p0] = w;
    w[0] = X[j].y; w[1] = Y[j].y; w[2] = Z[j].y; w[3] = 0.f; sp4[p0 + 1] = w;
  }
#pragma unroll
  for (int j = 0; j < 4; ++j)
    asm volatile("" : "+v"(X[j]), "+v"(Y[j]), "+v"(Z[j]));

  const float c0x = P[0], c0y = P[1], c0z = P[2];
  if (tid == 0) { scen[0] = c0x; scen[1] = c0y; scen[2] = c0z; }
  f32x2 E;
  float mv;
  {
#pragma clang fp contract(off)
    f32x2 vcx; vcx.x = c0x; vcx.y = c0x;
    f32x2 vcy; vcy.x = c0y; vcy.y = c0y;
    f32x2 vcz; vcz.x = c0z; vcz.y = c0z;
#pragma unroll
    for (int j = 0; j < 4; ++j) {
      f32x2 dx = X[j] - vcx, dy = Y[j] - vcy, dz = Z[j] - vcz;
      M[j] = (dx * dx + dy * dy) + dz * dz;
    }
    f32x2 A0 = __builtin_elementwise_max(M[0], M[1]);
    f32x2 A1 = __builtin_elementwise_max(M[2], M[3]);
    E = __builtin_elementwise_max(A0, A1);
    mv = fmaxf(E.x, E.y);
  }
  __syncthreads();   // sp4 visible

  for (int m = 1; m < MM; ++m) {
    const int pp = m & 1;
    float wmax = wave_fmax(mv);
    u64 bal = __ballot(mv == wmax);
    int L = (int)__builtin_ctzll(bal);        // lowest lane = lowest point range
    u32 e = 7u;
    if (M[3].y == wmax) e = 7u;
    if (M[3].x == wmax) e = 6u;
    if (M[2].y == wmax) e = 5u;
    if (M[2].x == wmax) e = 4u;
    if (M[1].y == wmax) e = 3u;
    if (M[1].x == wmax) e = 2u;
    if (M[0].y == wmax) e = 1u;
    if (M[0].x == wmax) e = 0u;
    if (lane == L) {
      u64 key = ((u64)__float_as_uint(wmax) << 32) | (u64)(u32)~(u32)(tid * 8 + (int)e);
      svk[pp][wv] = __builtin_bit_cast(double, key);
    }
    __syncthreads();
    const f64x2* kd = (const f64x2*)&svk[pp][0];
    f64x2 k0 = kd[0], k1 = kd[1], k2 = kd[2], k3 = kd[3];
    double q0 = fmax(k0.x, k0.y), q1 = fmax(k1.x, k1.y);
    double q2 = fmax(k2.x, k2.y), q3 = fmax(k3.x, k3.y);
    double kb = fmax(fmax(q0, q1), fmax(q2, q3));
    u32 bp = ~(u32)__builtin_bit_cast(u64, kb);
    f32x4 c4 = sp4[bp];                       // broadcast read
    if (tid == 0) {
      scen[m * 3 + 0] = c4[0];
      scen[m * 3 + 1] = c4[1];
      scen[m * 3 + 2] = c4[2];
    }
    {
#pragma clang fp contract(off)
      f32x2 vcx; vcx.x = c4[0]; vcx.y = c4[0];
      f32x2 vcy; vcy.x = c4[1]; vcy.y = c4[1];
      f32x2 vcz; vcz.x = c4[2]; vcz.y = c4[2];
#pragma unroll
      for (int j = 0; j < 4; ++j) {
        f32x2 dx = X[j] - vcx, dy = Y[j] - vcy, dz = Z[j] - vcz;
        f32x2 d2 = (dx * dx + dy * dy) + dz * dz;
        M[j] = __builtin_elementwise_min(M[j], d2);
      }
      f32x2 A0 = __builtin_elementwise_max(M[0], M[1]);
      f32x2 A1 = __builtin_elementwise_max(M[2], M[3]);
      E = __builtin_elementwise_max(A0, A1);
      mv = fmaxf(E.x, E.y);
    }
  }
  __syncthreads();
  for (int i = tid; i < MM * 3; i += 512)
    centers[(size_t)b * MM * 3 + i] = scen[i];
}

// ---------------- fused ball query + PointNetConv MLP: one block per center ----------------
// One-pass ball query: thread owns 16 contiguous points; DPP prefix-scan compaction.
__global__ __launch_bounds__(256) void sa_k(const float* __restrict__ x,
                                            const float* __restrict__ pos,
                                            const float* __restrict__ b1,
                                            const float* __restrict__ b2,
                                            const short* __restrict__ W1T,
                                            const short* __restrict__ W2T,
                                            const float* __restrict__ centers,
                                            float* __restrict__ out) {
  const int bid = blockIdx.x;
  const int cm = (bid & 7) * 1024 + (bid >> 3);   // XCD swizzle: one batch per XCD
  const int b = cm >> 10;
  const int tid = threadIdx.x;
  const int lane = tid & 63, wv = tid >> 6;
  const int l15 = lane & 15, lg = lane >> 4;

  __shared__ short s_feat[64][104];
  __shared__ short s_h1[64][136];
  __shared__ int s_nbr[64];
  __shared__ int s_wcnt[4];

  // --- weight fragments in registers (B-operand): row=n (lane&15), k contiguous 8 ---
  const int n0 = wv * 32;
  short8 w1f[2][3], w2f[2][4];
#pragma unroll
  for (int nt = 0; nt < 2; ++nt) {
    int row = n0 + nt * 16 + l15;
#pragma unroll
    for (int kt = 0; kt < 3; ++kt)
      w1f[nt][kt] = *reinterpret_cast<const short8*>(W1T + row * 104 + kt * 32 + lg * 8);
#pragma unroll
    for (int kt = 0; kt < 4; ++kt)
      w2f[nt][kt] = *reinterpret_cast<const short8*>(W2T + row * 136 + kt * 32 + lg * 8);
  }

  const float* Pb = pos + (size_t)b * NN * 3;
  const float cx = centers[(size_t)cm * 3 + 0];
  const float cy = centers[(size_t)cm * 3 + 1];
  const float cz = centers[(size_t)cm * 3 + 2];

  // --- one-pass ball query over own 16 points ---
  const int q0 = tid * 16;
  u32 hm = hit8(Pb + (size_t)q0 * 3, cx, cy, cz)
         | (hit8(Pb + (size_t)q0 * 3 + 24, cx, cy, cz) << 8);
  int c = __popc(hm);
  int inc = wave_iscan_add(c);
  if (lane == 63) s_wcnt[wv] = inc;           // wave total
  __syncthreads();
  int woff = 0, tot = 0;
#pragma unroll
  for (int w = 0; w < 4; ++w) {
    int t = s_wcnt[w];
    tot += t;
    if (w < wv) woff += t;
  }
  int cnt = tot > KK ? KK : tot;
  int slot = woff + inc - c;                  // exclusive, index-ordered
  // zero feat (pad cols + invalid rows) in same phase as s_nbr writes
  {
    int* fz = (int*)&s_feat[0][0];
    for (int i = tid; i < 64 * 104 / 2; i += 256) fz[i] = 0;
  }
#pragma unroll
  for (int i = 0; i < 16; ++i) {
    if (hm & (1u << i)) {
      if (slot < KK) s_nbr[slot] = q0 + i;
      ++slot;
    }
  }
  __syncthreads();

  // --- gather: 4 threads per neighbor, 16 feats each ---
  {
    const int j = tid >> 2, q = tid & 3;
    if (j < cnt) {
      int nj = s_nbr[j];
      const float* xr = x + ((size_t)b * NN + nj) * CC + q * 16;
      unsigned* dst = (unsigned*)&s_feat[j][q * 16];
#pragma unroll
      for (int v4 = 0; v4 < 4; ++v4) {
        f32x4 xv = *reinterpret_cast<const f32x4*>(xr + v4 * 4);
        unsigned lo0 = (unsigned)f2bf(xv[0]) | ((unsigned)f2bf(xv[1]) << 16);
        unsigned lo1 = (unsigned)f2bf(xv[2]) | ((unsigned)f2bf(xv[3]) << 16);
        dst[v4 * 2 + 0] = lo0;
        dst[v4 * 2 + 1] = lo1;
      }
      if (q == 0) {
        s_feat[j][64] = (short)f2bf(__fsub_rn(Pb[nj * 3 + 0], cx));
        s_feat[j][65] = (short)f2bf(__fsub_rn(Pb[nj * 3 + 1], cy));
        s_feat[j][66] = (short)f2bf(__fsub_rn(Pb[nj * 3 + 2], cz));
      }
    }
  }
  __syncthreads();

  // --- layer 1: feat[64x96] @ W1T -> h1[64][128] (per-wave 32 cols) ---
  f32x4 acc[4][2];
#pragma unroll
  for (int mt = 0; mt < 4; ++mt)
#pragma unroll
    for (int nt = 0; nt < 2; ++nt) acc[mt][nt] = (f32x4)0.f;

#pragma unroll
  for (int mt = 0; mt < 4; ++mt) {
    int arow = mt * 16 + l15;
#pragma unroll
    for (int kt = 0; kt < 3; ++kt) {
      short8 af = *reinterpret_cast<const short8*>(&s_feat[arow][kt * 32 + lg * 8]);
      acc[mt][0] = __builtin_amdgcn_mfma_f32_16x16x32_bf16(af, w1f[0][kt], acc[mt][0], 0, 0, 0);
      acc[mt][1] = __builtin_amdgcn_mfma_f32_16x16x32_bf16(af, w1f[1][kt], acc[mt][1], 0, 0, 0);
    }
  }

  // bias + relu -> bf16 h1 in LDS
#pragma unroll
  for (int mt = 0; mt < 4; ++mt) {
#pragma unroll
    for (int nt = 0; nt < 2; ++nt) {
      int col = n0 + nt * 16 + l15;
      float bias = b1[col];
#pragma unroll
      for (int r = 0; r < 4; ++r) {
        int row = mt * 16 + lg * 4 + r;
        float h = fmaxf(__fadd_rn(acc[mt][nt][r], bias), 0.f);
        s_h1[row][col] = (short)f2bf(h);
      }
    }
  }
  __syncthreads();

  // --- layer 2: h1[64x128] @ W2T ---
  f32x4 acc2[4][2];
#pragma unroll
  for (int mt = 0; mt < 4; ++mt)
#pragma unroll
    for (int nt = 0; nt < 2; ++nt) acc2[mt][nt] = (f32x4)0.f;

#pragma unroll
  for (int mt = 0; mt < 4; ++mt) {
    int arow = mt * 16 + l15;
#pragma unroll
    for (int kt = 0; kt < 4; ++kt) {
      short8 af = *reinterpret_cast<const short8*>(&s_h1[arow][kt * 32 + lg * 8]);
      acc2[mt][0] = __builtin_amdgcn_mfma_f32_16x16x32_bf16(af, w2f[0][kt], acc2[mt][0], 0, 0, 0);
      acc2[mt][1] = __builtin_amdgcn_mfma_f32_16x16x32_bf16(af, w2f[1][kt], acc2[mt][1], 0, 0, 0);
    }
  }

  // --- bias + relu + masked max over neighbors, then write out[cm][col] ---
#pragma unroll
  for (int nt = 0; nt < 2; ++nt) {
    int col = n0 + nt * 16 + l15;
    float bias = b2[col];
    float mx = -1e30f;
#pragma unroll
    for (int mt = 0; mt < 4; ++mt) {
#pragma unroll
      for (int r = 0; r < 4; ++r) {
        int row = mt * 16 + lg * 4 + r;
        float h = fmaxf(__fadd_rn(acc2[mt][nt][r], bias), 0.f);
        if (row < cnt) mx = fmaxf(mx, h);
      }
    }
    mx = fmaxf(mx, __shfl_xor(mx, 16));
    mx = fmaxf(mx, __shfl_xor(mx, 32));
    if (lg == 0) out[(size_t)cm * HH + col] = mx;
  }
}

extern "C" void kernel_launch(void* const* d_in, const int* in_sizes, int n_in,
                              void* d_out, int out_size, void* d_ws, size_t ws_size,
                              hipStream_t stream) {
  const float* x = (const float*)d_in[0];
  const float* pos = (const float*)d_in[1];
  const float* W1 = (const float*)d_in[2];
  const float* b1 = (const float*)d_in[3];
  const float* W2 = (const float*)d_in[4];
  const float* b2 = (const float*)d_in[5];

  float* out = (float*)d_out;
  float* centers = out + (size_t)BN * MM * HH;

  char* ws = (char*)d_ws;
  short* W1T = (short*)ws;                    // 128*104*2 = 26624 B
  short* W2T = (short*)(ws + 26624);          // 128*136*2 = 34816 B

  prep_w<<<68, 256, 0, stream>>>(W1, W2, W1T, W2T);
  fps_k<<<BN, 512, 0, stream>>>(pos, centers);
  sa_k<<<BN * MM, 256, 0, stream>>>(x, pos, b1, b2, W1T, W2T, centers, out);
}